// Round 8
// baseline (662.562 us; speedup 1.0000x reference)
//
#include <hip/hip_runtime.h>
#include <hip/hip_bf16.h>
#include <stdint.h>

#define TT   512
#define BB   128
#define DIN  256
#define DH   512
#define DOUT 256
#define NV   (BB*DH)     // 65536
#define NLOG (BB*DOUT)   // 32768
#define MTOT (TT*BB)     // 65536

typedef unsigned short u16;
typedef __attribute__((ext_vector_type(8))) short bf16x8;
typedef __attribute__((ext_vector_type(4))) float f32x4;

__device__ __forceinline__ void gld_lds16(const float* g, float* l) {
    __builtin_amdgcn_global_load_lds(
        (const __attribute__((address_space(1))) void*)g,
        (__attribute__((address_space(3))) void*)l, 16, 0, 0);
}

// ========== GEMM1: CUR = X @ Win + bin, strict f32 (bitwise-np) =============
// 128x256 tile, 256 threads, 8x16/thread (128 FMA per wave-kk -> LDS:FMA
// ratio ~72:256, near the 1:4 balance point of the shared LDS pipe), BK=16,
// double-buffered LDS, ONE barrier per k-step, B via global_load_lds.
// VGPR lessons: 512-thr blocks hard-cap at 128 regs (R5/R6 spilled);
// launch_bounds 2nd arg caps at 256/N (R4 spilled at 128). So: 256 threads,
// NO second launch_bounds arg -> natural ~160-200 regs, 2 waves/SIMD.
// Numerics: single accumulator per output, fmaf over k ASCENDING — bitwise
// vs numpy reference; spikes feed back through the threshold. DO NOT ALTER.
__global__ __launch_bounds__(256) void gemm1_f32(
    const float* __restrict__ X, const float* __restrict__ Win,
    const float* __restrict__ bin, float* __restrict__ CUR)
{
    __shared__ __align__(16) float As[2][16][132];   // [buf][k][m] (+4 pad)
    __shared__ __align__(16) float Bs[2][16][256];   // [buf][k][n] linear rows (gld_lds)
    const int bm = blockIdx.x * 128;
    const int bn = blockIdx.y * 256;
    const int t  = threadIdx.x;
    const int lane = t & 63, w = t >> 6;  // 4 waves
    const int tx = t & 15, ty = t >> 4;   // 16 col-groups x 16 row-groups
    float acc[8][16] = {};                // row ty*8+i, col g*64+tx*4+j
    float4 a4s[2];

    // B-tile 16x256: one LDS row = 1024 B = one gld_lds wave-instruction.
    // wave w, issue q -> row r = q*4+w; lane covers Bs[r][lane*4..+3].
    #define G1_STAGE_B(nb_, k0_) do { \
        _Pragma("unroll") \
        for (int q = 0; q < 4; ++q) { \
            const int r = q*4 + w; \
            gld_lds16(&Win[(size_t)((k0_)+r)*DH + bn + lane*4], &Bs[nb_][r][lane*4]); \
        } \
    } while (0)
    // A-tile 128x16: 2 float4/thread, reg-staged, transpose-written later.
    #define G1_LOAD_A(k0_) do { \
        _Pragma("unroll") \
        for (int p = 0; p < 2; ++p) { \
            const int f = p*256 + t; \
            const int row = f >> 2, q = f & 3; \
            a4s[p] = *reinterpret_cast<const float4*>( \
                &X[(size_t)(bm+row)*DIN + (k0_) + q*4]); \
        } \
    } while (0)
    #define G1_WRITE_A(nb_) do { \
        _Pragma("unroll") \
        for (int p = 0; p < 2; ++p) { \
            const int f = p*256 + t; \
            const int row = f >> 2, q = f & 3; \
            As[nb_][q*4+0][row] = a4s[p].x; As[nb_][q*4+1][row] = a4s[p].y; \
            As[nb_][q*4+2][row] = a4s[p].z; As[nb_][q*4+3][row] = a4s[p].w; \
        } \
    } while (0)

    // prologue: stage tile 0
    G1_STAGE_B(0, 0);
    G1_LOAD_A(0);
    G1_WRITE_A(0);
    __syncthreads();                      // drains vmcnt -> B tile 0 visible

    int nb = 0;
    for (int k0 = 0; k0 < DIN; k0 += 16) {
        const int nxt = k0 + 16;
        if (nxt < DIN) {                  // issue next-tile loads under compute
            G1_STAGE_B(nb^1, nxt);
            G1_LOAD_A(nxt);
        }
        #pragma unroll
        for (int kk = 0; kk < 16; ++kk) {
            float a[8], b[16];
            float4 a0 = *reinterpret_cast<const float4*>(&As[nb][kk][ty*8]);
            float4 a1 = *reinterpret_cast<const float4*>(&As[nb][kk][ty*8+4]);
            a[0]=a0.x; a[1]=a0.y; a[2]=a0.z; a[3]=a0.w;
            a[4]=a1.x; a[5]=a1.y; a[6]=a1.z; a[7]=a1.w;
            #pragma unroll
            for (int g = 0; g < 4; ++g) {   // b128, 16 addrs stride-16B: <=2-way
                float4 bq = *reinterpret_cast<const float4*>(&Bs[nb][kk][g*64 + tx*4]);
                b[g*4+0]=bq.x; b[g*4+1]=bq.y; b[g*4+2]=bq.z; b[g*4+3]=bq.w;
            }
            #pragma unroll
            for (int i = 0; i < 8; ++i)
                #pragma unroll
                for (int j = 0; j < 16; ++j)
                    acc[i][j] = fmaf(a[i], b[j], acc[i][j]);
        }
        if (nxt < DIN) G1_WRITE_A(nb^1);  // transpose-write A after compute
        __syncthreads();                  // one barrier per k-step
        nb ^= 1;
    }

    #pragma unroll
    for (int i = 0; i < 8; ++i) {
        const int row = bm + ty*8 + i;
        #pragma unroll
        for (int g = 0; g < 4; ++g) {
            const int col = bn + g*64 + tx*4;
            float4 o;
            o.x = __fadd_rn(acc[i][g*4+0], bin[col+0]);
            o.y = __fadd_rn(acc[i][g*4+1], bin[col+1]);
            o.z = __fadd_rn(acc[i][g*4+2], bin[col+2]);
            o.w = __fadd_rn(acc[i][g*4+3], bin[col+3]);
            *reinterpret_cast<float4*>(&CUR[(size_t)row*DH + col]) = o;
        }
    }
}

// ========== scan: strict-f32 recurrence, 32-deep load pipeline ==============
__global__ __launch_bounds__(256) void scan_k(
    const float* __restrict__ CUR, const float* __restrict__ wrec,
    u16* __restrict__ SPK, unsigned int* __restrict__ cnt)
{
    const int i = blockIdx.x*256 + threadIdx.x;
    float v = 0.0f;                       // V0 = 0
    const float w = wrec[i & (DH-1)];
    int c = 0;
    float cur[32], nxt[32];
    #pragma unroll
    for (int u = 0; u < 32; ++u) cur[u] = CUR[(size_t)u*NV + i];
    for (int t0 = 0; t0 < TT; t0 += 32) {
        if (t0 + 32 < TT) {
            #pragma unroll
            for (int u = 0; u < 32; ++u) nxt[u] = CUR[(size_t)(t0+32+u)*NV + i];
        }
        u16 sp[32];
        #pragma unroll
        for (int u = 0; u < 32; ++u) {
            const bool s = v > 1.0f;      // (V-1>0) <=> V>1 exactly in f32
            sp[u] = s ? (u16)0x3F80 : (u16)0;   // bf16 1.0 / 0.0
            c += (int)s;
            float t1 = __fmul_rn(0.9f, v);
            float t2 = __fadd_rn(t1, cur[u]);
            float t3 = __fadd_rn(t2, s ? w : 0.0f);
            v = __fsub_rn(t3, s ? 1.0f : 0.0f);
        }
        #pragma unroll
        for (int u = 0; u < 32; ++u) SPK[(size_t)(t0+u)*NV + i] = sp[u];
        #pragma unroll
        for (int u = 0; u < 32; ++u) cur[u] = nxt[u];
    }
    #pragma unroll
    for (int o = 32; o > 0; o >>= 1) c += __shfl_down(c, o, 64);
    if ((threadIdx.x & 63) == 0) atomicAdd(cnt, (unsigned int)c);
}

// ========== W_head -> bf16 transposed [DOUT][DH] ============================
__global__ __launch_bounds__(256) void trsp_k(
    const float* __restrict__ Wh, u16* __restrict__ WhT)
{
    const int id = blockIdx.x*256 + threadIdx.x;   // DOUT*DH
    const int n = id >> 9, k = id & (DH-1);
    __hip_bfloat16 h = __float2bfloat16(Wh[(size_t)k*DOUT + n]);
    WhT[id] = *reinterpret_cast<u16*>(&h);
}

// ========== GEMM2: logits = SPK @ Whead + bhead, bf16 MFMA ==================
// 128x128 tile, 4 waves (2x2), BK=32, 16x16x32 MFMA, double-buffered LDS,
// one barrier per k-step. Chunk XOR-swizzle c^(srow&3) kills frag-read
// bank conflicts.
__global__ __launch_bounds__(256) void gemm2_mfma(
    const u16* __restrict__ SPK, const u16* __restrict__ WhT,
    const float* __restrict__ bh, float* __restrict__ Y)
{
    __shared__ __align__(16) u16 Ab[2][128*32];
    __shared__ __align__(16) u16 Bb[2][128*32];
    const int bm = blockIdx.x * 128;
    const int bn = blockIdx.y * 128;
    const int t = threadIdx.x;
    const int lane = t & 63, wid = t >> 6;
    const int wr = wid >> 1, wc = wid & 1;
    const int srow = t >> 1, shf = t & 1;
    uint4 va[2], vb[2];
    f32x4 acc[4][4];
    #pragma unroll
    for (int m = 0; m < 4; ++m)
        #pragma unroll
        for (int n = 0; n < 4; ++n) acc[m][n] = (f32x4){0.f,0.f,0.f,0.f};

    #define G2_LOAD(k0) do { \
        _Pragma("unroll") \
        for (int q = 0; q < 2; ++q) { \
            const int c = shf*2 + q; \
            va[q] = *reinterpret_cast<const uint4*>(&SPK[(size_t)(bm+srow)*DH + (k0) + c*8]); \
            vb[q] = *reinterpret_cast<const uint4*>(&WhT[(size_t)(bn+srow)*DH + (k0) + c*8]); \
        } \
    } while (0)
    #define G2_WRITE(nb) do { \
        _Pragma("unroll") \
        for (int q = 0; q < 2; ++q) { \
            const int c = shf*2 + q; \
            *reinterpret_cast<uint4*>(&Ab[nb][srow*32 + ((c ^ (srow&3))*8)]) = va[q]; \
            *reinterpret_cast<uint4*>(&Bb[nb][srow*32 + ((c ^ (srow&3))*8)]) = vb[q]; \
        } \
    } while (0)

    G2_LOAD(0);
    G2_WRITE(0);
    __syncthreads();

    int nb = 0;
    for (int k0 = 0; k0 < DH; k0 += 32) {
        const int nxt = k0 + 32;
        if (nxt < DH) G2_LOAD(nxt);
        const int l15 = lane & 15, lc = lane >> 4;
        bf16x8 af[4], bfr[4];
        #pragma unroll
        for (int m = 0; m < 4; ++m) {
            const int r = wr*64 + m*16 + l15;
            af[m] = *reinterpret_cast<const bf16x8*>(&Ab[nb][r*32 + ((lc ^ (r&3))*8)]);
        }
        #pragma unroll
        for (int n = 0; n < 4; ++n) {
            const int r = wc*64 + n*16 + l15;
            bfr[n] = *reinterpret_cast<const bf16x8*>(&Bb[nb][r*32 + ((lc ^ (r&3))*8)]);
        }
        #pragma unroll
        for (int m = 0; m < 4; ++m)
            #pragma unroll
            for (int n = 0; n < 4; ++n)
                acc[m][n] = __builtin_amdgcn_mfma_f32_16x16x32_bf16(
                    af[m], bfr[n], acc[m][n], 0, 0, 0);
        if (nxt < DH) G2_WRITE(nb^1);
        __syncthreads();
        nb ^= 1;
    }
    // epilogue: D col = lane&15, row = (lane>>4)*4 + r
    #pragma unroll
    for (int m = 0; m < 4; ++m)
        #pragma unroll
        for (int n = 0; n < 4; ++n) {
            const int row0 = bm + wr*64 + m*16 + (lane >> 4)*4;
            const int col  = bn + wc*64 + n*16 + (lane & 15);
            const float bv = bh[col];
            #pragma unroll
            for (int r = 0; r < 4; ++r)
                Y[(size_t)(row0 + r)*DOUT + col] = acc[m][n][r] + bv;
        }
}

// ========== readout: mean over T (two-stage, deterministic) =================
__global__ __launch_bounds__(256) void readout1(
    const float* __restrict__ L, double* __restrict__ P)
{
    const int j = blockIdx.x*256 + threadIdx.x;
    const int p = blockIdx.y;
    double s = 0.0;
    for (int u = 0; u < 64; ++u)
        s += (double)L[(size_t)(p*64 + u)*NLOG + j];
    P[(size_t)p*NLOG + j] = s;
}
__global__ __launch_bounds__(256) void readout2(
    const double* __restrict__ P, float* __restrict__ R,
    const unsigned int* __restrict__ cnt, float* __restrict__ srate)
{
    const int j = blockIdx.x*256 + threadIdx.x;
    double s = 0.0;
    #pragma unroll
    for (int p = 0; p < 8; ++p) s += P[(size_t)p*NLOG + j];
    R[j] = (float)(s / (double)TT);
    if (j == 0)
        srate[0] = (float)((double)cnt[0] / ((double)TT * (double)NV));
}

// ============================================================================
extern "C" void kernel_launch(void* const* d_in, const int* in_sizes, int n_in,
                              void* d_out, int out_size, void* d_ws, size_t ws_size,
                              hipStream_t stream)
{
    const float* x     = (const float*)d_in[0];   // [512][128][256]
    const float* Win   = (const float*)d_in[1];   // [256][512]
    const float* bin   = (const float*)d_in[2];   // [512]
    const float* wrec  = (const float*)d_in[3];   // [512]
    const float* Whead = (const float*)d_in[4];   // [512][256]
    const float* bhead = (const float*)d_in[5];   // [256]

    float* out     = (float*)d_out;
    float* readout = out;                           // 32768
    float* logits  = out + NLOG;                    // 512*32768
    float* srate   = out + NLOG + (size_t)TT*NLOG;  // 1

    char* w = (char*)d_ws;
    size_t off = 0;
    float* CUR = (float*)(w + off);  off += (size_t)TT*NV*4;      // 128 MB
    u16*   SPK = (u16*)  (w + off);  off += (size_t)TT*NV*2;      //  64 MB
    u16*   WhT = (u16*)  (w + off);  off += (size_t)DOUT*DH*2;    // 256 KB
    double* P  = (double*)(w + off); off += (size_t)8*NLOG*8;     //   2 MB
    unsigned int* cnt = (unsigned int*)(w + off);

    hipMemsetAsync(cnt, 0, 256, stream);
    trsp_k<<<DOUT*DH/256, 256, 0, stream>>>(Whead, WhT);
    gemm1_f32<<<dim3(MTOT/128, DH/256), 256, 0, stream>>>(x, Win, bin, CUR);
    scan_k<<<NV/256, 256, 0, stream>>>(CUR, wrec, SPK, cnt);
    gemm2_mfma<<<dim3(MTOT/128, DOUT/128), 256, 0, stream>>>(SPK, WhT, bhead, logits);
    readout1<<<dim3(NLOG/256, 8), 256, 0, stream>>>(logits, P);
    readout2<<<NLOG/256, 256, 0, stream>>>(P, readout, cnt, srate);
}

// Round 9
// 388.621 us; speedup vs baseline: 1.7049x; 1.7049x over previous
//
#include <hip/hip_runtime.h>
#include <hip/hip_bf16.h>
#include <stdint.h>

#define TT   512
#define BB   128
#define DIN  256
#define DH   512
#define DOUT 256
#define NV   (BB*DH)     // 65536
#define NLOG (BB*DOUT)   // 32768
#define MTOT (TT*BB)     // 65536

typedef unsigned short u16;
typedef __attribute__((ext_vector_type(8))) short bf16x8;
typedef __attribute__((ext_vector_type(4))) float f32x4;

__device__ __forceinline__ void gld_lds16(const float* g, float* l) {
    __builtin_amdgcn_global_load_lds(
        (const __attribute__((address_space(1))) void*)g,
        (__attribute__((address_space(3))) void*)l, 16, 0, 0);
}

// ========== X transpose: X[MTOT][DIN] -> XT[DIN][MTOT] ======================
// Enables global_load_lds staging of A in [k][m] layout (gld_lds cannot
// transpose: wave-uniform LDS base + lane*16 only).
__global__ __launch_bounds__(256) void trspX_k(
    const float* __restrict__ X, float* __restrict__ XT)
{
    __shared__ float T[64][65];
    const int m0 = blockIdx.x * 64, k0 = blockIdx.y * 64;
    const int t = threadIdx.x;
    #pragma unroll
    for (int p = 0; p < 4; ++p) {
        const int idx = p*256 + t;
        const int rr = idx >> 4, cc = (idx & 15)*4;
        float4 v = *reinterpret_cast<const float4*>(
            &X[(size_t)(m0+rr)*DIN + k0 + cc]);
        T[rr][cc+0] = v.x; T[rr][cc+1] = v.y;
        T[rr][cc+2] = v.z; T[rr][cc+3] = v.w;
    }
    __syncthreads();
    #pragma unroll
    for (int p = 0; p < 4; ++p) {
        const int idx = p*256 + t;
        const int kk = idx >> 4, mm = (idx & 15)*4;
        float4 o;
        o.x = T[mm+0][kk]; o.y = T[mm+1][kk];
        o.z = T[mm+2][kk]; o.w = T[mm+3][kk];
        *reinterpret_cast<float4*>(&XT[(size_t)(k0+kk)*MTOT + m0 + mm]) = o;
    }
}

// ========== GEMM1: CUR = X @ Win + bin, strict f32 (bitwise-np) =============
// 128x256 tile, 256 threads, 8x16/thread, BK=16, double-buffered LDS, ONE
// barrier per k-step. BOTH A (from pre-transposed XT) and B staged via
// global_load_lds -> ZERO staging registers live across compute. Register
// ledger from R3-R8: acc(128)+24 staging regs spills in every bracket;
// acc(128)+0 staging fits (R7 precedent). No 2nd launch_bounds arg (VGPR-cap
// trap, R4/R5). Numerics: single accumulator per output, fmaf over k
// ASCENDING — bitwise vs numpy reference; spikes feed back. DO NOT ALTER.
__global__ __launch_bounds__(256) void gemm1_f32(
    const float* __restrict__ XT, const float* __restrict__ Win,
    const float* __restrict__ bin, float* __restrict__ CUR)
{
    __shared__ __align__(16) float As[2][16][128];   // [buf][k][m] linear (gld_lds)
    __shared__ __align__(16) float Bs[2][16][256];   // [buf][k][n] linear (gld_lds)
    const int bm = blockIdx.x * 128;
    const int bn = blockIdx.y * 256;
    const int t  = threadIdx.x;
    const int lane = t & 63, w = t >> 6;  // 4 waves
    const int tx = t & 15, ty = t >> 4;   // 16 col-groups x 16 row-groups
    float acc[8][16] = {};                // row ty*8+i, col g*64+tx*4+j

    // A-tile 16x128 ([k][m]): 1 gld_lds = 1KB = 2 rows. Wave w: rows 4w..4w+3.
    // lane<32 -> row rbase (+lane*16B); lane>=32 -> row rbase+1.
    #define G1_STAGE_A(nb_, k0_) do { \
        _Pragma("unroll") \
        for (int q = 0; q < 2; ++q) { \
            const int rbase = w*4 + q*2; \
            gld_lds16(&XT[(size_t)((k0_)+rbase+(lane>>5))*MTOT + bm + (lane&31)*4], \
                      &As[nb_][rbase][0]); \
        } \
    } while (0)
    // B-tile 16x256: 1 gld_lds = 1KB = 1 row. Wave w: rows q*4+w, q=0..3.
    #define G1_STAGE_B(nb_, k0_) do { \
        _Pragma("unroll") \
        for (int q = 0; q < 4; ++q) { \
            const int r = q*4 + w; \
            gld_lds16(&Win[(size_t)((k0_)+r)*DH + bn + lane*4], &Bs[nb_][r][0]); \
        } \
    } while (0)

    // prologue: stage tile 0
    G1_STAGE_A(0, 0);
    G1_STAGE_B(0, 0);
    __syncthreads();                      // drains vmcnt -> tile 0 visible

    int nb = 0;
    for (int k0 = 0; k0 < DIN; k0 += 16) {
        const int nxt = k0 + 16;
        if (nxt < DIN) {                  // issue next-tile loads under compute
            G1_STAGE_A(nb^1, nxt);
            G1_STAGE_B(nb^1, nxt);
        }
        #pragma unroll 4
        for (int kk = 0; kk < 16; ++kk) {
            float a[8], b[16];
            float4 a0 = *reinterpret_cast<const float4*>(&As[nb][kk][ty*8]);
            float4 a1 = *reinterpret_cast<const float4*>(&As[nb][kk][ty*8+4]);
            a[0]=a0.x; a[1]=a0.y; a[2]=a0.z; a[3]=a0.w;
            a[4]=a1.x; a[5]=a1.y; a[6]=a1.z; a[7]=a1.w;
            #pragma unroll
            for (int g = 0; g < 4; ++g) {   // 16 addrs x 16B, 4-way broadcast
                float4 bq = *reinterpret_cast<const float4*>(&Bs[nb][kk][g*64 + tx*4]);
                b[g*4+0]=bq.x; b[g*4+1]=bq.y; b[g*4+2]=bq.z; b[g*4+3]=bq.w;
            }
            #pragma unroll
            for (int i = 0; i < 8; ++i)
                #pragma unroll
                for (int j = 0; j < 16; ++j)
                    acc[i][j] = fmaf(a[i], b[j], acc[i][j]);
        }
        __syncthreads();                  // one barrier per k-step
        nb ^= 1;
    }

    #pragma unroll
    for (int i = 0; i < 8; ++i) {
        const int row = bm + ty*8 + i;
        #pragma unroll
        for (int g = 0; g < 4; ++g) {
            const int col = bn + g*64 + tx*4;
            float4 o;
            o.x = __fadd_rn(acc[i][g*4+0], bin[col+0]);
            o.y = __fadd_rn(acc[i][g*4+1], bin[col+1]);
            o.z = __fadd_rn(acc[i][g*4+2], bin[col+2]);
            o.w = __fadd_rn(acc[i][g*4+3], bin[col+3]);
            *reinterpret_cast<float4*>(&CUR[(size_t)row*DH + col]) = o;
        }
    }
}

// ========== scan: strict-f32 recurrence, 32-deep load pipeline ==============
__global__ __launch_bounds__(256) void scan_k(
    const float* __restrict__ CUR, const float* __restrict__ wrec,
    u16* __restrict__ SPK, unsigned int* __restrict__ cnt)
{
    const int i = blockIdx.x*256 + threadIdx.x;
    float v = 0.0f;                       // V0 = 0
    const float w = wrec[i & (DH-1)];
    int c = 0;
    float cur[32], nxt[32];
    #pragma unroll
    for (int u = 0; u < 32; ++u) cur[u] = CUR[(size_t)u*NV + i];
    for (int t0 = 0; t0 < TT; t0 += 32) {
        if (t0 + 32 < TT) {
            #pragma unroll
            for (int u = 0; u < 32; ++u) nxt[u] = CUR[(size_t)(t0+32+u)*NV + i];
        }
        u16 sp[32];
        #pragma unroll
        for (int u = 0; u < 32; ++u) {
            const bool s = v > 1.0f;      // (V-1>0) <=> V>1 exactly in f32
            sp[u] = s ? (u16)0x3F80 : (u16)0;   // bf16 1.0 / 0.0
            c += (int)s;
            float t1 = __fmul_rn(0.9f, v);
            float t2 = __fadd_rn(t1, cur[u]);
            float t3 = __fadd_rn(t2, s ? w : 0.0f);
            v = __fsub_rn(t3, s ? 1.0f : 0.0f);
        }
        #pragma unroll
        for (int u = 0; u < 32; ++u) SPK[(size_t)(t0+u)*NV + i] = sp[u];
        #pragma unroll
        for (int u = 0; u < 32; ++u) cur[u] = nxt[u];
    }
    #pragma unroll
    for (int o = 32; o > 0; o >>= 1) c += __shfl_down(c, o, 64);
    if ((threadIdx.x & 63) == 0) atomicAdd(cnt, (unsigned int)c);
}

// ========== W_head -> bf16 transposed [DOUT][DH] ============================
__global__ __launch_bounds__(256) void trsp_k(
    const float* __restrict__ Wh, u16* __restrict__ WhT)
{
    const int id = blockIdx.x*256 + threadIdx.x;   // DOUT*DH
    const int n = id >> 9, k = id & (DH-1);
    __hip_bfloat16 h = __float2bfloat16(Wh[(size_t)k*DOUT + n]);
    WhT[id] = *reinterpret_cast<u16*>(&h);
}

// ========== GEMM2: logits = SPK @ Whead + bhead, bf16 MFMA ==================
// 128x128 tile, 4 waves (2x2), BK=32, 16x16x32 MFMA, double-buffered LDS,
// one barrier per k-step. Chunk XOR-swizzle c^(srow&3) kills frag-read
// bank conflicts.
__global__ __launch_bounds__(256) void gemm2_mfma(
    const u16* __restrict__ SPK, const u16* __restrict__ WhT,
    const float* __restrict__ bh, float* __restrict__ Y)
{
    __shared__ __align__(16) u16 Ab[2][128*32];
    __shared__ __align__(16) u16 Bb[2][128*32];
    const int bm = blockIdx.x * 128;
    const int bn = blockIdx.y * 128;
    const int t = threadIdx.x;
    const int lane = t & 63, wid = t >> 6;
    const int wr = wid >> 1, wc = wid & 1;
    const int srow = t >> 1, shf = t & 1;
    uint4 va[2], vb[2];
    f32x4 acc[4][4];
    #pragma unroll
    for (int m = 0; m < 4; ++m)
        #pragma unroll
        for (int n = 0; n < 4; ++n) acc[m][n] = (f32x4){0.f,0.f,0.f,0.f};

    #define G2_LOAD(k0) do { \
        _Pragma("unroll") \
        for (int q = 0; q < 2; ++q) { \
            const int c = shf*2 + q; \
            va[q] = *reinterpret_cast<const uint4*>(&SPK[(size_t)(bm+srow)*DH + (k0) + c*8]); \
            vb[q] = *reinterpret_cast<const uint4*>(&WhT[(size_t)(bn+srow)*DH + (k0) + c*8]); \
        } \
    } while (0)
    #define G2_WRITE(nb) do { \
        _Pragma("unroll") \
        for (int q = 0; q < 2; ++q) { \
            const int c = shf*2 + q; \
            *reinterpret_cast<uint4*>(&Ab[nb][srow*32 + ((c ^ (srow&3))*8)]) = va[q]; \
            *reinterpret_cast<uint4*>(&Bb[nb][srow*32 + ((c ^ (srow&3))*8)]) = vb[q]; \
        } \
    } while (0)

    G2_LOAD(0);
    G2_WRITE(0);
    __syncthreads();

    int nb = 0;
    for (int k0 = 0; k0 < DH; k0 += 32) {
        const int nxt = k0 + 32;
        if (nxt < DH) G2_LOAD(nxt);
        const int l15 = lane & 15, lc = lane >> 4;
        bf16x8 af[4], bfr[4];
        #pragma unroll
        for (int m = 0; m < 4; ++m) {
            const int r = wr*64 + m*16 + l15;
            af[m] = *reinterpret_cast<const bf16x8*>(&Ab[nb][r*32 + ((lc ^ (r&3))*8)]);
        }
        #pragma unroll
        for (int n = 0; n < 4; ++n) {
            const int r = wc*64 + n*16 + l15;
            bfr[n] = *reinterpret_cast<const bf16x8*>(&Bb[nb][r*32 + ((lc ^ (r&3))*8)]);
        }
        #pragma unroll
        for (int m = 0; m < 4; ++m)
            #pragma unroll
            for (int n = 0; n < 4; ++n)
                acc[m][n] = __builtin_amdgcn_mfma_f32_16x16x32_bf16(
                    af[m], bfr[n], acc[m][n], 0, 0, 0);
        if (nxt < DH) G2_WRITE(nb^1);
        __syncthreads();
        nb ^= 1;
    }
    // epilogue: D col = lane&15, row = (lane>>4)*4 + r
    #pragma unroll
    for (int m = 0; m < 4; ++m)
        #pragma unroll
        for (int n = 0; n < 4; ++n) {
            const int row0 = bm + wr*64 + m*16 + (lane >> 4)*4;
            const int col  = bn + wc*64 + n*16 + (lane & 15);
            const float bv = bh[col];
            #pragma unroll
            for (int r = 0; r < 4; ++r)
                Y[(size_t)(row0 + r)*DOUT + col] = acc[m][n][r] + bv;
        }
}

// ========== readout: mean over T (two-stage, deterministic) =================
__global__ __launch_bounds__(256) void readout1(
    const float* __restrict__ L, double* __restrict__ P)
{
    const int j = blockIdx.x*256 + threadIdx.x;
    const int p = blockIdx.y;
    double s = 0.0;
    for (int u = 0; u < 64; ++u)
        s += (double)L[(size_t)(p*64 + u)*NLOG + j];
    P[(size_t)p*NLOG + j] = s;
}
__global__ __launch_bounds__(256) void readout2(
    const double* __restrict__ P, float* __restrict__ R,
    const unsigned int* __restrict__ cnt, float* __restrict__ srate)
{
    const int j = blockIdx.x*256 + threadIdx.x;
    double s = 0.0;
    #pragma unroll
    for (int p = 0; p < 8; ++p) s += P[(size_t)p*NLOG + j];
    R[j] = (float)(s / (double)TT);
    if (j == 0)
        srate[0] = (float)((double)cnt[0] / ((double)TT * (double)NV));
}

// ============================================================================
extern "C" void kernel_launch(void* const* d_in, const int* in_sizes, int n_in,
                              void* d_out, int out_size, void* d_ws, size_t ws_size,
                              hipStream_t stream)
{
    const float* x     = (const float*)d_in[0];   // [512][128][256]
    const float* Win   = (const float*)d_in[1];   // [256][512]
    const float* bin   = (const float*)d_in[2];   // [512]
    const float* wrec  = (const float*)d_in[3];   // [512]
    const float* Whead = (const float*)d_in[4];   // [512][256]
    const float* bhead = (const float*)d_in[5];   // [256]

    float* out     = (float*)d_out;
    float* readout = out;                           // 32768
    float* logits  = out + NLOG;                    // 512*32768
    float* srate   = out + NLOG + (size_t)TT*NLOG;  // 1

    char* w = (char*)d_ws;
    size_t off = 0;
    float* CUR = (float*)(w + off);  off += (size_t)TT*NV*4;      // 128 MB
    u16*   SPK = (u16*)  (w + off);  off += (size_t)TT*NV*2;      //  64 MB
    u16*   WhT = (u16*)  (w + off);  off += (size_t)DOUT*DH*2;    // 256 KB
    double* P  = (double*)(w + off); off += (size_t)8*NLOG*8;     //   2 MB
    unsigned int* cnt = (unsigned int*)(w + off);
    // XT (64 MB) overlays SPK: XT is consumed by gemm1, dead before scan
    // writes SPK. DIN*MTOT*4 == TT*NV*2 exactly.
    float* XT = (float*)SPK;

    hipMemsetAsync(cnt, 0, 256, stream);
    trspX_k<<<dim3(MTOT/64, DIN/64), 256, 0, stream>>>(x, XT);
    trsp_k<<<DOUT*DH/256, 256, 0, stream>>>(Whead, WhT);
    gemm1_f32<<<dim3(MTOT/128, DH/256), 256, 0, stream>>>(XT, Win, bin, CUR);
    scan_k<<<NV/256, 256, 0, stream>>>(CUR, wrec, SPK, cnt);
    gemm2_mfma<<<dim3(MTOT/128, DOUT/128), 256, 0, stream>>>(SPK, WhT, bhead, logits);
    readout1<<<dim3(NLOG/256, 8), 256, 0, stream>>>(logits, P);
    readout2<<<NLOG/256, 256, 0, stream>>>(P, readout, cnt, srate);
}